// Round 2
// baseline (107.763 us; speedup 1.0000x reference)
//
#include <hip/hip_runtime.h>

typedef float f32x16 __attribute__((ext_vector_type(16)));

#define HW      4096
#define CDIM    64
#define KCODES  512
#define PBLK    256      // positions per block
#define TPB     256      // threads per block
#define NPOS    131072

// Scaled scores: m_k = 256*(||e_k||^2 - 2 z.e_k) + 128  (always in [31,225] > 0)
// A = fp8(z), B = fp8(-512*e)  ->  mfma contributes 256*(-2 z.e)
// argmin via u32 min of (bits(m) & ~0x1FF) | k   (positive floats order as u32)
// loss_n = ||z_n||^2 + (minscore-128)/256;  total * 1.25/8388608

__global__ __launch_bounds__(TPB, 2)
void vqvae_kernel(const float* __restrict__ x,
                  const float* __restrict__ cb,
                  float* __restrict__ out,
                  float* __restrict__ loss_out)
{
    // B-fragments fp8(-512e): [chunk(32 codes)][kstep s][lane] -> 8 fp8 (8B)
    __shared__ unsigned long long cbB[16][4][64];   // 32 KB
    // A-fragments fp8(z): [posgroup(32 pos)][kstep s][lane]
    __shared__ unsigned long long zB [8][4][64];    // 16 KB
    __shared__ float    ecb[KCODES];                // 128 + 256*||e||^2
    __shared__ unsigned minu[PBLK];
    __shared__ float    red[4];

    const int t   = threadIdx.x;
    const int l   = t & 63;
    const int w   = t >> 6;
    const int n0  = blockIdx.x * PBLK;
    const int b   = n0 >> 12;          // 4096 positions per batch image
    const int hw0 = n0 & (HW - 1);

    // ---- Phase 0a: codebook fragments fp8(-512e), fragment-order in LDS ----
    #pragma unroll
    for (int j = 0; j < 16; ++j) {
        int slot  = t + TPB * j;           // 0..4095 = ((chunk*4+s)*64+lane)
        int lane  = slot & 63;
        int s     = (slot >> 6) & 3;
        int chunk = slot >> 8;
        int code  = chunk * 32 + (lane & 31);
        int c0    = s * 16 + (lane >> 5) * 8;
        const float4* p = (const float4*)(cb + code * CDIM + c0);
        float4 a0 = p[0], a1 = p[1];
        int w0, w1;
        w0 = __builtin_amdgcn_cvt_pk_fp8_f32(-512.f * a0.x, -512.f * a0.y, 0,  false);
        w0 = __builtin_amdgcn_cvt_pk_fp8_f32(-512.f * a0.z, -512.f * a0.w, w0, true);
        w1 = __builtin_amdgcn_cvt_pk_fp8_f32(-512.f * a1.x, -512.f * a1.y, 0,  false);
        w1 = __builtin_amdgcn_cvt_pk_fp8_f32(-512.f * a1.z, -512.f * a1.w, w1, true);
        cbB[chunk][s][lane] =
            ((unsigned long long)(unsigned)w1 << 32) | (unsigned long long)(unsigned)w0;
    }

    // ---- Phase 0b: ecb[k] = 128 + 256*||e_k||^2 (fp32) ----
    #pragma unroll
    for (int r = 0; r < 2; ++r) {
        int code = t + r * TPB;
        const float4* p = (const float4*)(cb + code * CDIM);
        float ssum = 0.f;
        #pragma unroll
        for (int q4 = 0; q4 < 16; ++q4) {
            float4 a = p[q4];
            ssum = fmaf(a.x, a.x, ssum); ssum = fmaf(a.y, a.y, ssum);
            ssum = fmaf(a.z, a.z, ssum); ssum = fmaf(a.w, a.w, ssum);
        }
        ecb[code] = 128.0f + 256.0f * ssum;
    }

    // ---- Phase 0c: z fragments fp8 + ||z||^2 (fp32); thread t <-> position t ----
    float zsq = 0.f;
    {
        const float* xb = x + (b * CDIM) * HW + hw0 + t;   // coalesced over t
        #pragma unroll
        for (int s = 0; s < 4; ++s)
        #pragma unroll
        for (int h = 0; h < 2; ++h) {
            float f[8];
            #pragma unroll
            for (int i = 0; i < 8; ++i) {
                f[i] = xb[(s * 16 + h * 8 + i) * HW];
                zsq = fmaf(f[i], f[i], zsq);
            }
            int w0, w1;
            w0 = __builtin_amdgcn_cvt_pk_fp8_f32(f[0], f[1], 0,  false);
            w0 = __builtin_amdgcn_cvt_pk_fp8_f32(f[2], f[3], w0, true);
            w1 = __builtin_amdgcn_cvt_pk_fp8_f32(f[4], f[5], 0,  false);
            w1 = __builtin_amdgcn_cvt_pk_fp8_f32(f[6], f[7], w1, true);
            zB[t >> 5][s][(t & 31) + 32 * h] =
                ((unsigned long long)(unsigned)w1 << 32) | (unsigned long long)(unsigned)w0;
        }
    }
    __syncthreads();

    // ---- Phase 1: MFMA 32x32x16 fp8 + in-register running u32-argmin ----
    long az0[4], az1[4];
    #pragma unroll
    for (int s = 0; s < 4; ++s) {
        az0[s] = (long)zB[2 * w + 0][s][l];
        az1[s] = (long)zB[2 * w + 1][s][l];
    }

    unsigned urun0[16], urun1[16];
    #pragma unroll
    for (int i = 0; i < 16; ++i) { urun0[i] = 0xFFFFFFFFu; urun1[i] = 0xFFFFFFFFu; }

    for (int chunk = 0; chunk < 16; ++chunk) {
        long b0 = (long)cbB[chunk][0][l];
        long b1 = (long)cbB[chunk][1][l];
        long b2 = (long)cbB[chunk][2][l];
        long b3 = (long)cbB[chunk][3][l];
        float bias = ecb[chunk * 32 + (l & 31)];
        f32x16 acc0, acc1;
        #pragma unroll
        for (int i = 0; i < 16; ++i) { acc0[i] = bias; acc1[i] = bias; }
        acc0 = __builtin_amdgcn_mfma_f32_32x32x16_fp8_fp8(az0[0], b0, acc0, 0, 0, 0);
        acc1 = __builtin_amdgcn_mfma_f32_32x32x16_fp8_fp8(az1[0], b0, acc1, 0, 0, 0);
        acc0 = __builtin_amdgcn_mfma_f32_32x32x16_fp8_fp8(az0[1], b1, acc0, 0, 0, 0);
        acc1 = __builtin_amdgcn_mfma_f32_32x32x16_fp8_fp8(az1[1], b1, acc1, 0, 0, 0);
        acc0 = __builtin_amdgcn_mfma_f32_32x32x16_fp8_fp8(az0[2], b2, acc0, 0, 0, 0);
        acc1 = __builtin_amdgcn_mfma_f32_32x32x16_fp8_fp8(az1[2], b2, acc1, 0, 0, 0);
        acc0 = __builtin_amdgcn_mfma_f32_32x32x16_fp8_fp8(az0[3], b3, acc0, 0, 0, 0);
        acc1 = __builtin_amdgcn_mfma_f32_32x32x16_fp8_fp8(az1[3], b3, acc1, 0, 0, 0);
        unsigned kor = (unsigned)(chunk * 32 + (l & 31));
        #pragma unroll
        for (int i = 0; i < 16; ++i) {
            unsigned u0 = (__float_as_uint(acc0[i]) & 0xFFFFFE00u) | kor;
            unsigned u1 = (__float_as_uint(acc1[i]) & 0xFFFFFE00u) | kor;
            urun0[i] = (u0 < urun0[i]) ? u0 : urun0[i];
            urun1[i] = (u1 < urun1[i]) ? u1 : urun1[i];
        }
    }

    // ---- Phase 2: cross-lane min over the 32 code-columns, publish per-position ----
    #pragma unroll
    for (int i = 0; i < 16; ++i) {
        unsigned u0 = urun0[i], u1 = urun1[i];
        #pragma unroll
        for (int m = 1; m <= 16; m <<= 1) {
            unsigned o0 = __shfl_xor(u0, m, 64);
            unsigned o1 = __shfl_xor(u1, m, 64);
            u0 = (o0 < u0) ? o0 : u0;
            u1 = (o1 < u1) ? o1 : u1;
        }
        urun0[i] = u0; urun1[i] = u1;
    }
    if ((l & 31) == 0) {
        int h = l >> 5;
        #pragma unroll
        for (int i = 0; i < 16; ++i) {
            int r = (i & 3) + 8 * (i >> 2) + 4 * h;
            minu[(2 * w + 0) * 32 + r] = urun0[i];
            minu[(2 * w + 1) * 32 + r] = urun1[i];
        }
    }
    __syncthreads();

    // ---- Phase 3: gather + coalesced store + loss ----
    unsigned u = minu[t];
    int   k      = (int)(u & 511u);
    float sprime = __uint_as_float(u & 0xFFFFFE00u);
    float lossv  = zsq + (sprime - 128.0f) * (1.0f / 256.0f);

    {
        float* ob = out + (b * CDIM) * HW + hw0 + t;   // coalesced over t
        int chunk = k >> 5;
        int klane = k & 31;
        #pragma unroll
        for (int s = 0; s < 4; ++s)
        #pragma unroll
        for (int h = 0; h < 2; ++h) {
            unsigned long long q = cbB[chunk][s][klane + 32 * h];  // fp8(-512e)
            int qlo = (int)(unsigned)(q & 0xFFFFFFFFull);
            int qhi = (int)(unsigned)(q >> 32);
            float v[8];
            v[0] = __builtin_amdgcn_cvt_f32_fp8(qlo, 0);
            v[1] = __builtin_amdgcn_cvt_f32_fp8(qlo, 1);
            v[2] = __builtin_amdgcn_cvt_f32_fp8(qlo, 2);
            v[3] = __builtin_amdgcn_cvt_f32_fp8(qlo, 3);
            v[4] = __builtin_amdgcn_cvt_f32_fp8(qhi, 0);
            v[5] = __builtin_amdgcn_cvt_f32_fp8(qhi, 1);
            v[6] = __builtin_amdgcn_cvt_f32_fp8(qhi, 2);
            v[7] = __builtin_amdgcn_cvt_f32_fp8(qhi, 3);
            #pragma unroll
            for (int i = 0; i < 8; ++i)
                ob[(s * 16 + h * 8 + i) * HW] = v[i] * (-1.0f / 512.0f);
        }
    }

    #pragma unroll
    for (int m = 1; m < 64; m <<= 1)
        lossv += __shfl_xor(lossv, m, 64);
    if (l == 0) red[w] = lossv;
    __syncthreads();
    if (t == 0) {
        float tot = red[0] + red[1] + red[2] + red[3];
        atomicAdd(loss_out, tot * (1.25f / 8388608.0f));
    }
}

extern "C" void kernel_launch(void* const* d_in, const int* in_sizes, int n_in,
                              void* d_out, int out_size, void* d_ws, size_t ws_size,
                              hipStream_t stream) {
    const float* x   = (const float*)d_in[0];
    const float* cb  = (const float*)d_in[1];
    float* out  = (float*)d_out;
    float* loss = out + (out_size - 1);   // scalar loss is the last element
    hipMemsetAsync(loss, 0, sizeof(float), stream);
    vqvae_kernel<<<dim3(NPOS / PBLK), dim3(TPB), 0, stream>>>(x, cb, out, loss);
}